// Round 7
// baseline (1239.245 us; speedup 1.0000x reference)
//
#include <hip/hip_runtime.h>
#include <hip/hip_fp16.h>
#include <math.h>

#define WW 128
#define HH 128
#define DD 128
#define HW (WW * HH)
#define VOL (WW * HH * DD)

typedef _Float16 f16x8 __attribute__((ext_vector_type(8)));
typedef _Float16 f16x4 __attribute__((ext_vector_type(4)));
typedef _Float16 f16x2 __attribute__((ext_vector_type(2)));
typedef float f32x4 __attribute__((ext_vector_type(4)));
typedef int int4v __attribute__((ext_vector_type(4)));

__device__ __forceinline__ float ldv(const float* p) { return *p; }
__device__ __forceinline__ float ldv(const _Float16* p) { return (float)*p; }
__device__ __forceinline__ void stv(float* p, float v) { *p = v; }
__device__ __forceinline__ void stv(_Float16* p, float v) { *p = (_Float16)v; }

// ==========================================================================
// cvt_x: planar fp32 (8ch) -> channel-interleaved f16x8 [d][h][w][c8]
// ==========================================================================
__global__ __launch_bounds__(256) void cvt_x(const float* __restrict__ x,
                                             _Float16* __restrict__ xi)
{
    const size_t v = (size_t)blockIdx.x * 256 + threadIdx.x;
    f16x8 o;
#pragma unroll
    for (int c = 0; c < 8; ++c) o[c] = (_Float16)x[(size_t)c * VOL + v];
    *(f16x8*)(xi + v * 8) = o;
}

// ==========================================================================
// Implicit-GEMM 3x3x3 conv via MFMA f16, input channel-interleaved f16x8.
//   D[OC, vox] = W[OC, K=216] * im2col[K, vox], K order k = tap*8 + c.
// Block tile 4d x 4h x 64w; halo 6x6x66 sites, ONE f16x8 load per site.
// R7: two n-tiles in flight per iteration (independent acc chains) to cover
// ds_read->MFMA->epilogue latency; kernel was latency-bound at 11% MfmaUtil.
// OM: 0 = interleaved 8-ch out, 1 = [vox][32] L1-normed weight field,
//     2 = planar 1-ch out.
// ==========================================================================
template <int OC, bool RELU, int OM, typename TO>
__global__ __launch_bounds__(256) void conv_mfma(const _Float16* __restrict__ in,
                                                 const float* __restrict__ wt,
                                                 const float* __restrict__ bias,
                                                 TO* __restrict__ out)
{
    __shared__ f16x8 hal[6 * 6 * 66];

    const int bid  = blockIdx.x;           // 2048 blocks: 32d x 32h x 2w
    const int wblk = bid & 1;
    const int hblk = (bid >> 1) & 31;
    const int dblk = bid >> 6;
    const int d0 = dblk * 4, h0 = hblk * 4, w0 = wblk * 64;

    const int tid = threadIdx.x;
    for (int s = tid; s < 6 * 6 * 66; s += 256) {
        const int dd = s / (6 * 66);
        const int r  = s % (6 * 66);
        const int hh = r / 66;
        const int ww = r % 66;
        const int gd = d0 + dd - 1, gh = h0 + hh - 1, gw = w0 + ww - 1;
        f16x8 v = {};
        if ((unsigned)gd < (unsigned)DD && (unsigned)gh < (unsigned)HH &&
            (unsigned)gw < (unsigned)WW)
            v = *(const f16x8*)(in + ((size_t)gd * HW + (size_t)gh * WW + gw) * 8);
        hal[s] = v;
    }

    const int lane = tid & 63;
    const int wid  = tid >> 6;             // wave id = local d slice
    const int n    = lane & 15;
    const int quad = lane >> 4;

    constexpr int MT = (OC > 16) ? 2 : 1;
    f16x8 afr[MT][7];
#pragma unroll
    for (int s = 0; s < 7; ++s) {
        const int tap = s * 4 + quad;      // k = tap*8 + c
#pragma unroll
        for (int mt = 0; mt < MT; ++mt) {
            const int m = mt * 16 + n;
            f16x8 a = {};
            if (tap < 27 && m < OC) {
#pragma unroll
                for (int j = 0; j < 8; ++j)
                    a[j] = (_Float16)wt[(size_t)m * 216 + (size_t)j * 27 + tap];
            }
            afr[mt][s] = a;
        }
    }

    int boff[7];
#pragma unroll
    for (int s = 0; s < 7; ++s) {
        int tap = s * 4 + quad;
        if (tap > 26) tap = 26;            // A is zero there
        const int kd = tap / 9, kh = (tap % 9) / 3, kw = tap % 3;
        boff[s] = (wid + kd) * (6 * 66) + kh * 66 + kw + n;
    }

    float bv[MT][4];
#pragma unroll
    for (int mt = 0; mt < MT; ++mt)
#pragma unroll
        for (int r = 0; r < 4; ++r) {
            const int o = mt * 16 + quad * 4 + r;
            bv[mt][r] = ((OM != 1) && bias != nullptr && o < OC) ? bias[o] : 0.f;
        }

    __syncthreads();

    const size_t outbase = (size_t)(d0 + wid) * HW + (size_t)h0 * WW + w0;

#pragma unroll 1
    for (int it = 0; it < 8; ++it) {       // 8 iters x 2 n-tiles of 16 voxels
        const int nt0 = it * 2;
        const int add0 = (nt0 >> 2) * 66 + (nt0 & 3) * 16;
        const int add1 = ((nt0 + 1) >> 2) * 66 + ((nt0 + 1) & 3) * 16;
        f32x4 acc[2][MT];
#pragma unroll
        for (int half = 0; half < 2; ++half)
#pragma unroll
            for (int mt = 0; mt < MT; ++mt) {
                acc[half][mt][0] = bv[mt][0]; acc[half][mt][1] = bv[mt][1];
                acc[half][mt][2] = bv[mt][2]; acc[half][mt][3] = bv[mt][3];
            }
#pragma unroll
        for (int s = 0; s < 7; ++s) {
            const f16x8 b0 = hal[boff[s] + add0];
            const f16x8 b1 = hal[boff[s] + add1];
            acc[0][0] = __builtin_amdgcn_mfma_f32_16x16x32_f16(afr[0][s], b0, acc[0][0], 0, 0, 0);
            acc[1][0] = __builtin_amdgcn_mfma_f32_16x16x32_f16(afr[0][s], b1, acc[1][0], 0, 0, 0);
            if (MT > 1) {
                acc[0][1] = __builtin_amdgcn_mfma_f32_16x16x32_f16(afr[1][s], b0, acc[0][1], 0, 0, 0);
                acc[1][1] = __builtin_amdgcn_mfma_f32_16x16x32_f16(afr[1][s], b1, acc[1][1], 0, 0, 0);
            }
        }
#pragma unroll
        for (int half = 0; half < 2; ++half) {
            const int nt = nt0 + half;
            const int hl = nt >> 2, wseg = nt & 3;
            const size_t vox = outbase + (size_t)hl * WW + wseg * 16 + n;
            if (OM == 0) {
                if (quad < 2) {
                    f16x4 o4;
#pragma unroll
                    for (int r = 0; r < 4; ++r) {
                        float v = acc[half][0][r];
                        if (RELU) v = fmaxf(v, 0.f);
                        o4[r] = (_Float16)v;
                    }
                    *(f16x4*)((_Float16*)out + vox * 8 + quad * 4) = o4;
                }
            } else if (OM == 1) {
                float ssum = 0.f;
#pragma unroll
                for (int mt = 0; mt < MT; ++mt)
#pragma unroll
                    for (int r = 0; r < 4; ++r) ssum += fabsf(acc[half][mt][r]);
                ssum += __shfl_xor(ssum, 16);
                ssum += __shfl_xor(ssum, 32);
                const float inv = 1.0f / fmaxf(ssum, 1e-12f);
                int p[2][2];
#pragma unroll
                for (int mt = 0; mt < MT; ++mt)
#pragma unroll
                    for (int rr = 0; rr < 2; ++rr) {
                        f16x2 t;
                        t[0] = (_Float16)(acc[half][mt][2 * rr] * inv);
                        t[1] = (_Float16)(acc[half][mt][2 * rr + 1] * inv);
                        p[mt][rr] = __builtin_bit_cast(int, t);
                    }
                int4v wv;
#pragma unroll
                for (int w = 0; w < 4; ++w) {
                    const int sq = (2 * quad + (w >> 1)) & 3;
                    const int bidx = ((sq << 4) | n) << 2;
                    const int a0 = __builtin_amdgcn_ds_bpermute(bidx, p[0][w & 1]);
                    const int a1 = __builtin_amdgcn_ds_bpermute(bidx, p[1][w & 1]);
                    wv[w] = (quad < 2) ? a0 : a1;
                }
                *(int4v*)((_Float16*)out + (vox << 5) + (quad << 3)) = wv;
            } else { // OM == 2, OC = 1 planar
                if (quad == 0) {
                    float v = acc[half][0][0];
                    if (RELU) v = fmaxf(v, 0.f);
                    stv((TO*)out + vox, v);
                }
            }
        }
    }
}

// ==========================================================================
// adapt8: per-voxel 27-tap weights [vox][32] fp16, 8 interleaved channels.
// R7: thread = 2 adjacent w-voxels — the 4 shifted row loads serve both
// voxels (18 loads/voxel instead of 27), 16 independent acc chains.
// ==========================================================================
__global__ __launch_bounds__(256) void adapt8(const _Float16* __restrict__ in,
                                              const _Float16* __restrict__ wn,
                                              _Float16* __restrict__ out)
{
    const int tid = threadIdx.x;
    const int bid = blockIdx.x;            // 4096 = 128 d x 32 h-quads
    const int d  = bid >> 5;
    const int h  = ((bid & 31) << 2) + (tid >> 6);
    const int w2 = (tid & 63) << 1;        // voxels w2, w2+1
    const size_t vox = (size_t)d * HW + (size_t)h * WW + w2;

    const f16x8* wr0 = (const f16x8*)(wn + (vox << 5));
    f16x8 wk0[4], wk1[4];
#pragma unroll
    for (int j = 0; j < 4; ++j) { wk0[j] = wr0[j]; wk1[j] = wr0[4 + j]; }

    float acc[2][8];
#pragma unroll
    for (int v = 0; v < 2; ++v)
#pragma unroll
        for (int c = 0; c < 8; ++c) acc[v][c] = 0.f;

#pragma unroll
    for (int kd = 0; kd < 3; ++kd) {
        const int gd = d + kd - 1;
#pragma unroll
        for (int kh = 0; kh < 3; ++kh) {
            const int gh = h + kh - 1;
            const bool rowok = ((unsigned)gd < (unsigned)DD) &&
                               ((unsigned)gh < (unsigned)HH);
            const _Float16* rp = in + ((size_t)gd * HW + (size_t)gh * WW) * 8;
            f16x8 xs[4];   // shifts w2-1 .. w2+2
#pragma unroll
            for (int j = 0; j < 4; ++j) {
                const int gw = w2 + j - 1;
                xs[j] = f16x8{};
                if (rowok && (unsigned)gw < (unsigned)WW)
                    xs[j] = *(const f16x8*)(rp + (size_t)gw * 8);
            }
            const int kb = kd * 9 + kh * 3;
#pragma unroll
            for (int kw = 0; kw < 3; ++kw) {
                const int t = kb + kw;
                const float w0v = (float)wk0[t >> 3][t & 7];
                const float w1v = (float)wk1[t >> 3][t & 7];
#pragma unroll
                for (int c = 0; c < 8; ++c) {
                    acc[0][c] += w0v * (float)xs[kw][c];
                    acc[1][c] += w1v * (float)xs[kw + 1][c];
                }
            }
        }
    }
#pragma unroll
    for (int v = 0; v < 2; ++v) {
        f16x8 o;
#pragma unroll
        for (int c = 0; c < 8; ++c) o[c] = (_Float16)acc[v][c];
        *(f16x8*)(out + (vox + v) * 8) = o;
    }
}

// ==========================================================================
// adapt1: 1 channel, planar in/out; weights [vox][32]. Thread = 1 voxel.
// ==========================================================================
template <typename TOUT>
__global__ __launch_bounds__(256) void adapt1(const _Float16* __restrict__ in,
                                              const _Float16* __restrict__ wn,
                                              TOUT* __restrict__ out)
{
    const size_t vox = (size_t)blockIdx.x * 256 + threadIdx.x;
    const int w = (int)(vox & 127);
    const int h = (int)((vox >> 7) & 127);
    const int d = (int)(vox >> 14);

    const f16x8* wrow = (const f16x8*)(wn + (vox << 5));
    f16x8 wkv[4];
#pragma unroll
    for (int j = 0; j < 4; ++j) wkv[j] = wrow[j];

    float acc = 0.f;
#pragma unroll
    for (int kd = 0; kd < 3; ++kd) {
        const int gd = d + kd - 1;
#pragma unroll
        for (int kh = 0; kh < 3; ++kh) {
            const int gh = h + kh - 1;
#pragma unroll
            for (int kw = 0; kw < 3; ++kw) {
                const int gw = w + kw - 1;
                const bool ok = ((unsigned)gd < (unsigned)DD) &&
                                ((unsigned)gh < (unsigned)HH) &&
                                ((unsigned)gw < (unsigned)WW);
                float xv = 0.f;
                if (ok)
                    xv = (float)in[(size_t)gd * HW + (size_t)gh * WW + gw];
                const int t = kd * 9 + kh * 3 + kw;
                acc += (float)wkv[t >> 3][t & 7] * xv;
            }
        }
    }
    stv(out + vox, acc);
}

extern "C" void kernel_launch(void* const* d_in, const int* in_sizes, int n_in,
                              void* d_out, int out_size, void* d_ws, size_t ws_size,
                              hipStream_t stream)
{
    (void)in_sizes; (void)n_in; (void)out_size; (void)ws_size;

    const float* x      = (const float*)d_in[0];
    const float* ac1_w1 = (const float*)d_in[1];
    const float* ac1_b1 = (const float*)d_in[2];
    const float* ac1_w2 = (const float*)d_in[3];
    const float* ac2_w1 = (const float*)d_in[4];
    const float* ac2_b1 = (const float*)d_in[5];
    const float* ac2_w2 = (const float*)d_in[6];
    const float* ac3_w1 = (const float*)d_in[7];
    const float* ac3_b1 = (const float*)d_in[8];
    const float* ac3_w2 = (const float*)d_in[9];
    const float* mid_w  = (const float*)d_in[10];
    const float* mid_b  = (const float*)d_in[11];
    const float* out_w  = (const float*)d_in[12];
    const float* out_b  = (const float*)d_in[13];
    float* outp = (float*)d_out;

    // fp16 scratch, 192 MB total:
    // Wb = [vox][32] weight field (32V) | B1i = 8V interleaved | B2i = 8V interleaved
    const size_t V = (size_t)VOL;
    _Float16* Wb  = (_Float16*)d_ws;
    _Float16* B1i = Wb + 32 * V;
    _Float16* B2i = B1i + 8 * V;
    _Float16* F0  = B2i;        // block-3 planar 1-ch ping-pong (B2i free there)
    _Float16* F1  = B2i + V;

    const dim3 cgrid(2048), cblk(256);
    const dim3 a8grid(4096), a8blk(256);
    const dim3 a1grid(8192), a1blk(256);

    cvt_x<<<8192, 256, 0, stream>>>(x, B2i);                                    // B2i = x (interleaved)

    // ---- adaptive block 1 (input x = B2i) ----
    conv_mfma<8, true, 0, _Float16><<<cgrid, cblk, 0, stream>>>(B2i, ac1_w1, ac1_b1, B1i);
    conv_mfma<27, false, 1, _Float16><<<cgrid, cblk, 0, stream>>>(B1i, ac1_w2, nullptr, Wb);
    adapt8<<<a8grid, a8blk, 0, stream>>>(B2i, Wb, B1i);
    adapt8<<<a8grid, a8blk, 0, stream>>>(B1i, Wb, B2i);
    adapt8<<<a8grid, a8blk, 0, stream>>>(B2i, Wb, B1i);                         // B1i = block1 out
    conv_mfma<8, false, 0, _Float16><<<cgrid, cblk, 0, stream>>>(B1i, mid_w, mid_b, B2i); // B2i = mid

    // ---- adaptive block 2 (input mid = B2i) ----
    conv_mfma<8, true, 0, _Float16><<<cgrid, cblk, 0, stream>>>(B2i, ac2_w1, ac2_b1, B1i);
    conv_mfma<27, false, 1, _Float16><<<cgrid, cblk, 0, stream>>>(B1i, ac2_w2, nullptr, Wb);
    adapt8<<<a8grid, a8blk, 0, stream>>>(B2i, Wb, B1i);
    adapt8<<<a8grid, a8blk, 0, stream>>>(B1i, Wb, B2i);
    adapt8<<<a8grid, a8blk, 0, stream>>>(B2i, Wb, B1i);                         // B1i = mid2

    // ---- block 3: weights from mid2 = B1i ----
    conv_mfma<8, true, 0, _Float16><<<cgrid, cblk, 0, stream>>>(B1i, ac3_w1, ac3_b1, B2i);
    conv_mfma<27, false, 1, _Float16><<<cgrid, cblk, 0, stream>>>(B2i, ac3_w2, nullptr, Wb);
    conv_mfma<1, false, 2, _Float16><<<cgrid, cblk, 0, stream>>>(B1i, out_w, out_b, F0);
    adapt1<_Float16><<<a1grid, a1blk, 0, stream>>>(F0, Wb, F1);
    adapt1<_Float16><<<a1grid, a1blk, 0, stream>>>(F1, Wb, F0);
    adapt1<float><<<a1grid, a1blk, 0, stream>>>(F0, Wb, outp);
}